// Round 1
// baseline (5716.224 us; speedup 1.0000x reference)
//
#include <hip/hip_runtime.h>
#include <math.h>

// ConvLSTM: B=8, T=16, C=8, H=W=128, F=32, 3x3 kernels.
// z = conv(x_t, Wk, VALID) + conv(h, Uk, SAME) + b   (128 = 4*F out-channels)
// i,f,o = hard_sigmoid; g = tanh; c = f*c + i*tanh(g); h = o*tanh(c)
// Output: h after T steps, shape (8, 32, 126, 126) fp32.

#define B_ 8
#define T_ 16
#define C_ 8
#define H_ 128
#define W_ 128
#define F_ 32
#define HO 126
#define WO 126
#define TS 16

__global__ __launch_bounds__(256) void convlstm_step(
    const float* __restrict__ x, int t,
    const float* __restrict__ Wk,
    const float* __restrict__ Uk,
    const float* __restrict__ bias,
    const float* __restrict__ h_in,
    const float* __restrict__ c_in,
    float* __restrict__ h_out,
    float* __restrict__ c_out)
{
    __shared__ float xs[C_][18][18];
    __shared__ float hs[F_][18][18];

    const int x0 = blockIdx.x * TS;
    const int y0 = blockIdx.y * TS;
    const int bb = blockIdx.z;
    const int tid = threadIdx.x;

    const float* xt = x + ((size_t)(bb * T_ + t) * C_ * H_ * W_);

    // stage x tile: input rows y0..y0+17, cols x0..x0+17 (VALID conv reads y..y+2)
    for (int i = tid; i < C_ * 18 * 18; i += 256) {
        int c = i / 324;
        int r = i % 324;
        int ry = r / 18, rx = r % 18;
        int gy = y0 + ry, gx = x0 + rx;
        float v = 0.f;
        if (gy < H_ && gx < W_) v = xt[(c * H_ + gy) * W_ + gx];
        xs[c][ry][rx] = v;
    }
    // stage h tile with 1-px zero pad (SAME conv reads y-1..y+1)
    const float* hb = h_in + (size_t)bb * F_ * HO * WO;
    for (int i = tid; i < F_ * 18 * 18; i += 256) {
        int c = i / 324;
        int r = i % 324;
        int ry = r / 18, rx = r % 18;
        int gy = y0 + ry - 1, gx = x0 + rx - 1;
        float v = 0.f;
        if (gy >= 0 && gy < HO && gx >= 0 && gx < WO) v = hb[(c * HO + gy) * WO + gx];
        hs[c][ry][rx] = v;
    }
    __syncthreads();

    const int ty = tid >> 4;
    const int tx = tid & 15;
    const int oy = y0 + ty, ox = x0 + tx;
    if (oy >= HO || ox >= WO) return;   // only sync above; safe to exit

    const size_t base = ((size_t)bb * F_) * (size_t)(HO * WO) + (size_t)oy * WO + ox;

    for (int fp = 0; fp < F_; fp += 2) {
        float acc[2][4];
        #pragma unroll
        for (int g = 0; g < 4; ++g) {
            acc[0][g] = bias[g * F_ + fp];
            acc[1][g] = bias[g * F_ + fp + 1];
        }
        // x-conv (VALID): 8 in-ch * 3x3, 2 out-state-ch * 4 gates per LDS read
        #pragma unroll
        for (int c = 0; c < C_; ++c) {
            #pragma unroll
            for (int ky = 0; ky < 3; ++ky) {
                #pragma unroll
                for (int kx = 0; kx < 3; ++kx) {
                    float v = xs[c][ty + ky][tx + kx];
                    #pragma unroll
                    for (int g = 0; g < 4; ++g) {
                        acc[0][g] += v * Wk[(((g * F_ + fp) * C_ + c) * 3 + ky) * 3 + kx];
                        acc[1][g] += v * Wk[(((g * F_ + fp + 1) * C_ + c) * 3 + ky) * 3 + kx];
                    }
                }
            }
        }
        // h-conv (SAME): 32 in-ch * 3x3
        for (int fc = 0; fc < F_; ++fc) {
            #pragma unroll
            for (int ky = 0; ky < 3; ++ky) {
                #pragma unroll
                for (int kx = 0; kx < 3; ++kx) {
                    float v = hs[fc][ty + ky][tx + kx];
                    #pragma unroll
                    for (int g = 0; g < 4; ++g) {
                        acc[0][g] += v * Uk[(((g * F_ + fp) * F_ + fc) * 3 + ky) * 3 + kx];
                        acc[1][g] += v * Uk[(((g * F_ + fp + 1) * F_ + fc) * 3 + ky) * 3 + kx];
                    }
                }
            }
        }
        #pragma unroll
        for (int j = 0; j < 2; ++j) {
            int f = fp + j;
            float zi = acc[j][0], zf = acc[j][1], zg = acc[j][2], zo = acc[j][3];
            float ig = fminf(fmaxf(0.2f * zi + 0.5f, 0.f), 1.f);
            float fg = fminf(fmaxf(0.2f * zf + 0.5f, 0.f), 1.f);
            float og = fminf(fmaxf(0.2f * zo + 0.5f, 0.f), 1.f);
            float gg = tanhf(zg);
            size_t idx = base + (size_t)f * (HO * WO);
            float cn = fg * c_in[idx] + ig * gg;
            c_out[idx] = cn;
            h_out[idx] = og * tanhf(cn);
        }
    }
}

extern "C" void kernel_launch(void* const* d_in, const int* in_sizes, int n_in,
                              void* d_out, int out_size, void* d_ws, size_t ws_size,
                              hipStream_t stream) {
    const float* x    = (const float*)d_in[0];
    const float* Wk   = (const float*)d_in[1];
    const float* Uk   = (const float*)d_in[2];
    const float* bias = (const float*)d_in[3];
    float* out = (float*)d_out;

    const size_t N = (size_t)B_ * F_ * HO * WO;  // 4,064,256 state elements
    float* h0 = (float*)d_ws;
    float* h1 = h0 + N;
    float* cb = h1 + N;   // needs ws_size >= 3*N*4 ~= 49 MB

    hipMemsetAsync(h0, 0, N * sizeof(float), stream);
    hipMemsetAsync(cb, 0, N * sizeof(float), stream);

    dim3 grid(8, 8, B_);   // x-tiles, y-tiles (ceil(126/16)=8), batch
    dim3 block(256);
    for (int t = 0; t < T_; ++t) {
        const float* hin = (t & 1) ? h1 : h0;
        float* hout = (t == T_ - 1) ? out : ((t & 1) ? h0 : h1);
        convlstm_step<<<grid, block, 0, stream>>>(x, t, Wk, Uk, bias, hin, cb, hout, cb);
    }
}

// Round 2
// 537.529 us; speedup vs baseline: 10.6343x; 10.6343x over previous
//
#include <hip/hip_runtime.h>
#include <hip/hip_bf16.h>

typedef __bf16 bf16_t;
typedef __attribute__((ext_vector_type(8))) __bf16 bf16x8;
typedef __attribute__((ext_vector_type(4))) __bf16 bf16x4;
typedef __attribute__((ext_vector_type(16))) float f32x16;
typedef unsigned int u32;

#define B_ 8
#define T_ 16
#define C_ 8
#define F_ 32
#define H_ 128
#define W_ 128
#define HO 126
#define WO 126

// LDS layout (bytes):
//  x_s  [10][18][8c]  bf16 : row*288 + col*16 + c*2          @ 0     (2880 B)
//  h_s  [4fg][10][18][8f]  : fg*2880 + row*288 + col*16 + f*2 @ 2880  (11520 B)
//  Bbuf 2 x 4096 (fragment-linear [nt][lane][j])              @ 14400 (8192 B)
#define XS_OFF 0
#define HS_OFF 2880
#define BB_OFF 14400
#define LDS_BYTES 22592
#define NKK 23   // 5 x-part k16 steps (K=72 pad 80) + 18 h-part (K=288)

// -------- B prepack: Bp[kk][nt][lane][j] bf16, exact MFMA B-fragment order.
// n = nt*32 + (lane&31); k_local = (lane>>5)*8 + j.
// x part (kk<5): p = 2*kk + (lane>>5) in-channel-group, c = j;  p>8 -> 0
// h part       : q = (kk-5)>>1 (ky*3+kx), f = ((kk-5)&1)*16 + (lane>>5)*8 + j
__global__ __launch_bounds__(256) void prep_B(const float* __restrict__ Wk,
                                              const float* __restrict__ Uk,
                                              bf16_t* __restrict__ Bp) {
    int e = blockIdx.x * 256 + threadIdx.x;   // grid sized exactly 23*2048
    int j = e & 7, lane = (e >> 3) & 63, nt = (e >> 9) & 3, kk = e >> 11;
    int n = nt * 32 + (lane & 31), half = lane >> 5;
    float v = 0.f;
    if (kk < 5) {
        int p = 2 * kk + half, c = j;
        if (p <= 8) v = Wk[((n * C_ + c) * 3 + p / 3) * 3 + (p % 3)];
    } else {
        int kk2 = kk - 5, q = kk2 >> 1;
        int f = ((kk2 & 1) << 4) + (half << 3) + j;
        v = Uk[((n * F_ + f) * 3 + q / 3) * 3 + (q % 3)];
    }
    Bp[e] = (bf16_t)v;
}

__global__ __launch_bounds__(256, 3) void lstm_step(
    const float* __restrict__ x, int t,
    const bf16_t* __restrict__ Bp,
    const float* __restrict__ bias,
    const float* __restrict__ h_in,   // [b][y][x][f] fp32
    float* __restrict__ c_st,         // [b][y][x][f] fp32, in-place
    float* __restrict__ h_out)        // [b][y][x][f] fp32
{
    __shared__ __align__(16) unsigned char smem[LDS_BYTES];
    const int tid = threadIdx.x;
    const int w = tid >> 6, l = tid & 63;
    const int bx = blockIdx.x, by = blockIdx.y, bb = blockIdx.z;
    const int r0 = by * 8, c0 = bx * 16;

    // ---- stage x tile: NCHW fp32 -> LDS bf16 [row][col][c] ----
    const float* xb = x + (size_t)(bb * T_ + t) * (C_ * H_ * W_);
    for (int i = tid; i < 1440; i += 256) {
        int c = i / 180, rem = i % 180;
        int row = rem / 18, col = rem % 18;
        int gy = r0 + row, gx = c0 + col;
        float v = 0.f;
        if (gy < H_ && gx < W_) v = xb[(c * H_ + gy) * W_ + gx];
        *(bf16_t*)(smem + XS_OFF + row * 288 + col * 16 + c * 2) = (bf16_t)v;
    }
    // ---- stage h tile: NHWC fp32 -> LDS bf16 [fg][row][col][8f], SAME pad ----
    const float* hb = h_in + (size_t)bb * (HO * WO * F_);
    for (int i = tid; i < 1440; i += 256) {
        int pix = i >> 3, fq = i & 7;            // fq = float4 group (4 ch)
        int row = pix / 18, col = pix % 18;
        int gy = r0 - 1 + row, gx = c0 - 1 + col;
        float4 v = make_float4(0.f, 0.f, 0.f, 0.f);
        if (gy >= 0 && gy < HO && gx >= 0 && gx < WO)
            v = *(const float4*)(hb + (size_t)(gy * WO + gx) * F_ + fq * 4);
        bf16x4 pv = {(bf16_t)v.x, (bf16_t)v.y, (bf16_t)v.z, (bf16_t)v.w};
        *(bf16x4*)(smem + HS_OFF + (fq >> 1) * 2880 + row * 288 + col * 16 + (fq & 1) * 8) = pv;
    }

    const int fch = l & 31, half = l >> 5;
    const int rtA = (l >> 4) & 1, colA = l & 15;
    const int rt_full = 2 * w + rtA;               // pixel row in 8-row tile
    const int baseX = rt_full * 288 + colA * 16;
    const int baseH = HS_OFF + half * 2880 + baseX;
    const int baseB = BB_OFF + l * 16;

    f32x16 acc[4];
    #pragma unroll
    for (int nt = 0; nt < 4; ++nt) {
        float bv = bias[nt * 32 + fch];
        #pragma unroll
        for (int j = 0; j < 16; ++j) acc[nt][j] = bv;
    }

    // prefetch B panel 0 (each wave loads its nt = w quarter, 1 KB)
    {
        const unsigned char* src = (const unsigned char*)Bp + (w << 10) + l * 16;
        __builtin_amdgcn_global_load_lds((const __attribute__((address_space(1))) u32*)src,
            (__attribute__((address_space(3))) u32*)(smem + BB_OFF + (w << 10)), 16, 0, 0);
    }
    __syncthreads();   // drains vmcnt+lgkmcnt: staging + panel0 visible

    constexpr int OFFP[10] = {0, 16, 32, 288, 304, 320, 576, 592, 608, 864};

    #pragma unroll
    for (int kk = 0; kk < NKK; ++kk) {
        if (kk + 1 < NKK) {
            const unsigned char* src =
                (const unsigned char*)Bp + (((kk + 1) * 4 + w) << 10) + l * 16;
            __builtin_amdgcn_global_load_lds((const __attribute__((address_space(1))) u32*)src,
                (__attribute__((address_space(3))) u32*)(smem + BB_OFF + (((kk + 1) & 1) << 12) + (w << 10)),
                16, 0, 0);
        }
        int aoff;
        if (kk < 5) {
            // p = 2*kk + half; p==9 reads garbage (B is zero there) - safe, in-bounds
            aoff = baseX + (half ? OFFP[2 * kk + 1] : OFFP[2 * kk]);
        } else {
            const int kk2 = kk - 5, q = kk2 >> 1;
            aoff = baseH + (kk2 & 1) * 5760 + (q / 3) * 288 + (q % 3) * 16;
        }
        bf16x8 av = *(const bf16x8*)(smem + aoff);
        const int bbs = baseB + ((kk & 1) << 12);
        bf16x8 b0 = *(const bf16x8*)(smem + bbs);
        bf16x8 b1 = *(const bf16x8*)(smem + bbs + 1024);
        bf16x8 b2 = *(const bf16x8*)(smem + bbs + 2048);
        bf16x8 b3 = *(const bf16x8*)(smem + bbs + 3072);
        acc[0] = __builtin_amdgcn_mfma_f32_32x32x16_bf16(av, b0, acc[0], 0, 0, 0);
        acc[1] = __builtin_amdgcn_mfma_f32_32x32x16_bf16(av, b1, acc[1], 0, 0, 0);
        acc[2] = __builtin_amdgcn_mfma_f32_32x32x16_bf16(av, b2, acc[2], 0, 0, 0);
        acc[3] = __builtin_amdgcn_mfma_f32_32x32x16_bf16(av, b3, acc[3], 0, 0, 0);
        __syncthreads();   // panel kk+1 landed; buf[kk&1] free for kk+2 prefetch
    }

    // ---- fused LSTM epilogue: acc[nt] = gate nt (i,f,g,o) for channel fch ----
    float* cb = c_st + (size_t)bb * (HO * WO * F_);
    float* ho = h_out + (size_t)bb * (HO * WO * F_);
    #pragma unroll
    for (int r = 0; r < 16; ++r) {
        const int m = (r & 3) + ((r >> 2) << 3) + (half << 2);   // C/D row map
        const int gy = r0 + 2 * w + (m >> 4), gx = c0 + (m & 15);
        if (gy < HO && gx < WO) {
            const int pidx = (gy * WO + gx) * F_ + fch;
            float zi = acc[0][r], zf = acc[1][r], zg = acc[2][r], zo = acc[3][r];
            float ig = fminf(fmaxf(0.2f * zi + 0.5f, 0.f), 1.f);
            float fg = fminf(fmaxf(0.2f * zf + 0.5f, 0.f), 1.f);
            float og = fminf(fmaxf(0.2f * zo + 0.5f, 0.f), 1.f);
            float eg = __expf(2.f * zg);
            float tg = 1.f - 2.f / (eg + 1.f);
            float cn = fg * cb[pidx] + ig * tg;
            cb[pidx] = cn;
            float ec = __expf(2.f * cn);
            ho[pidx] = og * (1.f - 2.f / (ec + 1.f));
        }
    }
}

// ---- final h: NHWC fp32 -> NCHW fp32 ----
__global__ __launch_bounds__(256) void out_transpose(const float* __restrict__ h,
                                                     float* __restrict__ out) {
    __shared__ float tile[WO * 33];
    const int gy = blockIdx.x, bb = blockIdx.y;
    const float* hp = h + ((size_t)bb * HO + gy) * (WO * F_);
    for (int i = threadIdx.x; i < WO * F_; i += 256) {
        int gx = i >> 5, f = i & 31;
        tile[gx * 33 + f] = hp[i];
    }
    __syncthreads();
    float* op = out + (size_t)bb * (F_ * HO * WO) + (size_t)gy * WO;
    for (int i = threadIdx.x; i < WO * F_; i += 256) {
        int f = i / WO, gx = i % WO;
        op[(size_t)f * (HO * WO) + gx] = tile[gx * 33 + f];
    }
}

extern "C" void kernel_launch(void* const* d_in, const int* in_sizes, int n_in,
                              void* d_out, int out_size, void* d_ws, size_t ws_size,
                              hipStream_t stream) {
    const float* x    = (const float*)d_in[0];
    const float* Wk   = (const float*)d_in[1];
    const float* Uk   = (const float*)d_in[2];
    const float* bias = (const float*)d_in[3];
    float* out = (float*)d_out;

    const size_t N = (size_t)B_ * HO * WO * F_;   // 4,064,256 state elems
    float* h0 = (float*)d_ws;
    float* h1 = h0 + N;
    float* c  = h1 + N;
    bf16_t* Bp = (bf16_t*)(c + N);                // 94,208 B; total ws ~48.9 MB

    hipMemsetAsync(h0, 0, N * sizeof(float), stream);
    hipMemsetAsync(c, 0, N * sizeof(float), stream);
    prep_B<<<184, 256, 0, stream>>>(Wk, Uk, Bp);  // 184*256 == 23*2048 exactly

    dim3 grid(8, 16, B_);   // x-tiles(16 cols), y-tiles(8 rows), batch
    for (int t = 0; t < T_; ++t) {
        const float* hin = (t & 1) ? h1 : h0;
        float* hout = (t & 1) ? h0 : h1;
        lstm_step<<<grid, 256, 0, stream>>>(x, t, Bp, bias, hin, c, hout);
    }
    out_transpose<<<dim3(HO, B_), 256, 0, stream>>>(h0, out);  // t=15 wrote h0
}